// Round 9
// baseline (38.422 us; speedup 1.0000x reference)
//
#include <hip/hip_runtime.h>
#include <hip/hip_fp16.h>

#define NPART 500000
#define MPART 450000
#define NBXC 1024
#define NBYC 1024
#define KROW 7                  // w,h < 6.0 -> window spans at most 7 bins/axis
#define NBLK_PART 1954          // ceil(500000/256)

// Tiled field layout: 4x4-cell tiles (64B), tile (tx,ty) at cell-index
// ((tx*256)+ty)*16, within-tile row-major (x&3)*4 + (y&3).
// A window's loads then touch ~2x2 mostly-used tiles (~3 cache lines)
// instead of 4-5 sparse 128B row-lines (round-8 lesson: lines, not loads,
// are the binding resource).
__device__ __forceinline__ int tiled_idx(int x, int y) {
    return (((x >> 2) * 256 + (y >> 2)) << 4) + ((x & 3) << 2) + (y & 3);
}

// ---------------------------------------------------------------------------
// Kernel A: velocity field, vectorized 4 cells/thread along y.
// Each thread's 4 cells = one within-tile row -> single float4 tiled store.
// ---------------------------------------------------------------------------
__global__ __launch_bounds__(256) void field_kernel(const float* __restrict__ pot,
                                                    const float* __restrict__ rho,
                                                    __half2* __restrict__ v,
                                                    float* __restrict__ partials) {
    const int idx = blockIdx.x * 256 + threadIdx.x;      // 0 .. 262143
    const int i  = idx >> 8;                             // row 0..1023
    const int ty = idx & 255;                            // y-tile 0..255
    const int j4 = ty << 2;                              // col 0,4,..,1020

    const int ip = min(i + 1, NBXC - 1);
    const int im = max(i - 1, 0);
    const float sx = (ip - im == 2) ? 0.5f : 1.0f;

    const float4 c  = *reinterpret_cast<const float4*>(pot + i  * NBYC + j4);
    const float4 cu = *reinterpret_cast<const float4*>(pot + ip * NBYC + j4);
    const float4 cd = *reinterpret_cast<const float4*>(pot + im * NBYC + j4);
    const float  cl = pot[i * NBYC + max(j4 - 1, 0)];
    const float  cr = pot[i * NBYC + min(j4 + 4, NBYC - 1)];
    const float4 r4 = *reinterpret_cast<const float4*>(rho + i * NBYC + j4);

    const float vx0 = -(cu.x - cd.x) * sx;
    const float vx1 = -(cu.y - cd.y) * sx;
    const float vx2 = -(cu.z - cd.z) * sx;
    const float vx3 = -(cu.w - cd.w) * sx;

    const float vy0 = (j4 == 0)             ? -(c.y - c.x) : -(c.y - cl) * 0.5f;
    const float vy1 = -(c.z - c.x) * 0.5f;
    const float vy2 = -(c.w - c.y) * 0.5f;
    const float vy3 = (j4 + 3 == NBYC - 1)  ? -(c.w - c.z) : -(cr - c.z) * 0.5f;

    float4 st;
    st.x = __builtin_bit_cast(float, __floats2half2_rn(vx0, vy0));
    st.y = __builtin_bit_cast(float, __floats2half2_rn(vx1, vy1));
    st.z = __builtin_bit_cast(float, __floats2half2_rn(vx2, vy2));
    st.w = __builtin_bit_cast(float, __floats2half2_rn(vx3, vy3));
    // tiled store: within-tile row (i&3) of tile (i>>2, ty)
    *reinterpret_cast<float4*>(v + ((((i >> 2) * 256 + ty) << 4) + ((i & 3) << 2))) = st;

    float e = r4.x * (vx0 * vx0 + vy0 * vy0)
            + r4.y * (vx1 * vx1 + vy1 * vy1)
            + r4.z * (vx2 * vx2 + vy2 * vy2)
            + r4.w * (vx3 * vx3 + vy3 * vy3);
    #pragma unroll
    for (int off = 32; off > 0; off >>= 1) e += __shfl_down(e, off, 64);
    __shared__ float smem[4];
    const int lane = threadIdx.x & 63;
    const int wid  = threadIdx.x >> 6;
    if (lane == 0) smem[wid] = e;
    __syncthreads();
    if (threadIdx.x == 0) partials[blockIdx.x] = (smem[0] + smem[1]) + (smem[2] + smem[3]);
}

// ---------------------------------------------------------------------------
// Kernel C: per-particle gradient (blocks 0..1953) + energy reduction
// (block 1954). Round-6 exec-masked row loop, tiled addressing: per active
// x, the 4-cell y-groups live at +0B/+64B/+128B within adjacent tiles.
// ---------------------------------------------------------------------------
__global__ __launch_bounds__(256) void particle_kernel(const float* __restrict__ pos,
                                                       const float* __restrict__ nsx,
                                                       const float* __restrict__ nsy,
                                                       const __half2* __restrict__ v,
                                                       const float* __restrict__ partials,
                                                       float* __restrict__ out) {
    __shared__ float smem[4];

    if (blockIdx.x == NBLK_PART) {      // ---- energy reduction block ----
        const int t = threadIdx.x;
        float e = (partials[t] + partials[t + 256]) + (partials[t + 512] + partials[t + 768]);
        #pragma unroll
        for (int off = 32; off > 0; off >>= 1) e += __shfl_down(e, off, 64);
        const int lane = t & 63;
        const int wid  = t >> 6;
        if (lane == 0) smem[wid] = e;
        __syncthreads();
        if (t == 0) out[0] = 0.5f * ((smem[0] + smem[1]) + (smem[2] + smem[3]));
        return;
    }

    const int i = blockIdx.x * 256 + threadIdx.x;
    if (i >= NPART) return;
    if (i >= MPART) {                   // zero pad regions [M:N), [N+M:2N)
        out[1 + i]         = 0.0f;
        out[1 + NPART + i] = 0.0f;
        return;
    }

    const float px = pos[i];
    const float py = pos[NPART + i];
    const float w  = nsx[i];
    const float h  = nsy[i];

    float gpx, gpy;
    const bool large = (w >= 1.0f) || (h >= 1.0f);
    if (!large) {
        int ix = min(max((int)floorf(px), 0), NBXC - 1);
        int iy = min(max((int)floorf(py), 0), NBYC - 1);
        const float wx = fminf(fmaxf(px - (float)ix, 0.0f), 1.0f);
        const float wy = fminf(fmaxf(py - (float)iy, 0.0f), 1.0f);
        const int ix1 = min(ix + 1, NBXC - 1);
        const int iy1 = min(iy + 1, NBYC - 1);
        const float2 f00 = __half22float2(v[tiled_idx(ix,  iy )]);
        const float2 f10 = __half22float2(v[tiled_idx(ix1, iy )]);
        const float2 f01 = __half22float2(v[tiled_idx(ix,  iy1)]);
        const float2 f11 = __half22float2(v[tiled_idx(ix1, iy1)]);
        const float w00 = (1.0f - wx) * (1.0f - wy);
        const float w10 = wx * (1.0f - wy);
        const float w01 = (1.0f - wx) * wy;
        const float w11 = wx * wy;
        gpx = w00 * f00.x + w10 * f10.x + w01 * f01.x + w11 * f11.x;
        gpy = w00 * f00.y + w10 * f10.y + w01 * f01.y + w11 * f11.y;
    } else {
        const float lx = px - 0.5f * w, rx = px + 0.5f * w;
        const float ly = py - 0.5f * h, ry = py + 0.5f * h;
        const int bminx = min(max((int)floorf(lx), 0), NBXC - 1);
        const int bmaxx = min(max((int)floorf(rx), 0), NBXC - 1);
        const int bminy = min(max((int)floorf(ly), 0), NBYC - 1);
        const int bmaxy = min(max((int)floorf(ry), 0), NBYC - 1);
        // 4-cell-aligned y-window start, clamped so all 12 cells stay in-grid.
        const int by0   = min(bminy & ~3, NBYC - 12);
        const int ty0   = by0 >> 2;                 // first y-tile (<= 253)
        const int ncell = bmaxy - by0;              // last active cell index, 0..11

        float oy[12];
        #pragma unroll
        for (int k = 0; k < 12; ++k) {
            const int b = by0 + k;
            const float bl = (float)b;
            float ov = fminf(ry, bl + 1.0f) - fmaxf(ly, bl);
            oy[k] = (b <= bmaxy && ov > 0.0f) ? ov : 0.0f;
        }

        const float4 z = make_float4(0.0f, 0.0f, 0.0f, 0.0f);
        float afx = 0.0f, afy = 0.0f;
        #pragma unroll
        for (int k = 0; k < KROW; ++k) {
            const int b = bminx + k;
            const float bl = (float)b;
            float ov = fminf(rx, bl + 1.0f) - fmaxf(lx, bl);
            ov = (b <= bmaxx && ov > 0.0f) ? ov : 0.0f;
            if (ov == 0.0f) continue;          // exec-masked: inactive rows load nothing
            const int bx = min(b, NBXC - 1);
            // within-tile row (bx&3) of tiles (bx>>2, ty0 + r); r-step = +16 cells (64B)
            const __half2* bp = v + ((((bx >> 2) * 256 + ty0) << 4) + ((bx & 3) << 2));
            float4 q0 = *reinterpret_cast<const float4*>(bp);
            float4 q1 = (ncell >= 4) ? *reinterpret_cast<const float4*>(bp + 16) : z;
            float4 q2 = (ncell >= 8) ? *reinterpret_cast<const float4*>(bp + 32) : z;
            const float* a0 = &q0.x;
            const float* a1 = &q1.x;
            const float* a2 = &q2.x;
            float sx = 0.0f, sy = 0.0f;
            #pragma unroll
            for (int e = 0; e < 4; ++e) {
                const float2 f = __half22float2(__builtin_bit_cast(__half2, a0[e]));
                sx += f.x * oy[e];
                sy += f.y * oy[e];
            }
            #pragma unroll
            for (int e = 0; e < 4; ++e) {
                const float2 f = __half22float2(__builtin_bit_cast(__half2, a1[e]));
                sx += f.x * oy[4 + e];
                sy += f.y * oy[4 + e];
            }
            #pragma unroll
            for (int e = 0; e < 4; ++e) {
                const float2 f = __half22float2(__builtin_bit_cast(__half2, a2[e]));
                sx += f.x * oy[8 + e];
                sy += f.y * oy[8 + e];
            }
            afx += sx * ov;
            afy += sy * ov;
        }
        const float inv = 1.0f / fmaxf(w * h, 1e-30f);
        gpx = afx * inv;
        gpy = afy * inv;
    }
    out[1 + i]         = gpx;
    out[1 + NPART + i] = gpy;
}

extern "C" void kernel_launch(void* const* d_in, const int* in_sizes, int n_in,
                              void* d_out, int out_size, void* d_ws, size_t ws_size,
                              hipStream_t stream) {
    const float* pos = (const float*)d_in[0];
    const float* pot = (const float*)d_in[1];
    const float* rho = (const float*)d_in[2];
    const float* nsx = (const float*)d_in[3];
    const float* nsy = (const float*)d_in[4];
    float* out = (float*)d_out;

    __half2* v      = (__half2*)d_ws;                                     // 4 MB (tiled)
    float* partials = (float*)((char*)d_ws + (size_t)NBXC * NBYC * sizeof(__half2));

    field_kernel<<<(NBXC * NBYC / 4) / 256, 256, 0, stream>>>(pot, rho, v, partials);
    particle_kernel<<<NBLK_PART + 1, 256, 0, stream>>>(pos, nsx, nsy, v, partials, out);
}

// Round 10
// 30.009 us; speedup vs baseline: 1.2803x; 1.2803x over previous
//
#include <hip/hip_runtime.h>
#include <hip/hip_fp16.h>

#define NPART 500000
#define MPART 450000
#define NBXC 1024
#define NBYC 1024
#define NBLK_PART 1954          // ceil(500000/256)
#define NPARTIAL 512            // field blocks

// Tiled field layout: 2x8-cell tiles (2 x-rows x 8 y-cells x 4B = 64B = one
// L2 sector). Tile (tx,ty), tx=x>>1 (512), ty=y>>3 (128), tx-major so that
// (tx,ty) and (tx,ty+1) are adjacent (+64B, same 128B line).
// cell index = ((tx*128 + ty)*16) + (x&1)*8 + (y&7)
__device__ __forceinline__ int tidx(int x, int y) {
    return ((((x >> 1) * 128 + (y >> 3)) << 4) + ((x & 1) << 3) + (y & 7));
}

// ---------------------------------------------------------------------------
// Kernel A: velocity field. One thread = one tile-row (row x, cells
// j0..j0+7) -> 32B contiguous store. 512 blocks -> partials[512].
// ---------------------------------------------------------------------------
__global__ __launch_bounds__(256) void field_kernel(const float* __restrict__ pot,
                                                    const float* __restrict__ rho,
                                                    __half2* __restrict__ v,
                                                    float* __restrict__ partials) {
    const int idx = blockIdx.x * 256 + threadIdx.x;      // 0 .. 131071
    const int x  = idx >> 7;                             // row 0..1023
    const int ty = idx & 127;                            // y-tile 0..127
    const int j0 = ty << 3;                              // col 0,8,..,1016

    const int ip = min(x + 1, NBXC - 1);
    const int im = max(x - 1, 0);
    const float sx = (ip - im == 2) ? 0.5f : 1.0f;

    const float4* pc = reinterpret_cast<const float4*>(pot + x  * NBYC + j0);
    const float4* pu = reinterpret_cast<const float4*>(pot + ip * NBYC + j0);
    const float4* pd = reinterpret_cast<const float4*>(pot + im * NBYC + j0);
    const float4* pr = reinterpret_cast<const float4*>(rho + x  * NBYC + j0);
    float c[8], u[8], d[8], r[8];
    *reinterpret_cast<float4*>(c)     = pc[0]; *reinterpret_cast<float4*>(c + 4) = pc[1];
    *reinterpret_cast<float4*>(u)     = pu[0]; *reinterpret_cast<float4*>(u + 4) = pu[1];
    *reinterpret_cast<float4*>(d)     = pd[0]; *reinterpret_cast<float4*>(d + 4) = pd[1];
    *reinterpret_cast<float4*>(r)     = pr[0]; *reinterpret_cast<float4*>(r + 4) = pr[1];
    const float cl = pot[x * NBYC + max(j0 - 1, 0)];
    const float cr = pot[x * NBYC + min(j0 + 8, NBYC - 1)];

    float vx[8], vy[8];
    #pragma unroll
    for (int k = 0; k < 8; ++k) vx[k] = -(u[k] - d[k]) * sx;
    vy[0] = (j0 == 0) ? -(c[1] - c[0]) : -(c[1] - cl) * 0.5f;
    #pragma unroll
    for (int k = 1; k < 7; ++k) vy[k] = -(c[k + 1] - c[k - 1]) * 0.5f;
    vy[7] = (j0 + 7 == NBYC - 1) ? -(c[7] - c[6]) : -(cr - c[6]) * 0.5f;

    float st[8];
    #pragma unroll
    for (int k = 0; k < 8; ++k)
        st[k] = __builtin_bit_cast(float, __floats2half2_rn(vx[k], vy[k]));
    // contiguous 32B store: row (x&1) of tile (x>>1, ty)
    float4* vp = reinterpret_cast<float4*>(v + ((((x >> 1) * 128 + ty) << 4) + ((x & 1) << 3)));
    vp[0] = *reinterpret_cast<float4*>(st);
    vp[1] = *reinterpret_cast<float4*>(st + 4);

    float e = 0.0f;
    #pragma unroll
    for (int k = 0; k < 8; ++k) e += r[k] * (vx[k] * vx[k] + vy[k] * vy[k]);
    #pragma unroll
    for (int off = 32; off > 0; off >>= 1) e += __shfl_down(e, off, 64);
    __shared__ float smem[4];
    const int lane = threadIdx.x & 63;
    const int wid  = threadIdx.x >> 6;
    if (lane == 0) smem[wid] = e;
    __syncthreads();
    if (threadIdx.x == 0) partials[blockIdx.x] = (smem[0] + smem[1]) + (smem[2] + smem[3]);
}

// ---------------------------------------------------------------------------
// Kernel C: per-particle gradient (blocks 0..1953) + energy reduction
// (block 1954). Window processed as <=4 x-row-pairs x <=2 y-tiles; each
// touched tile = exactly one 64B sector, all its loads consecutive.
// Pair skipped (exec-masked) when both row weights are 0.
// ---------------------------------------------------------------------------
__global__ __launch_bounds__(256) void particle_kernel(const float* __restrict__ pos,
                                                       const float* __restrict__ nsx,
                                                       const float* __restrict__ nsy,
                                                       const __half2* __restrict__ v,
                                                       const float* __restrict__ partials,
                                                       float* __restrict__ out) {
    __shared__ float smem[4];

    if (blockIdx.x == NBLK_PART) {      // ---- energy reduction block ----
        const int t = threadIdx.x;
        float e = partials[t] + partials[t + 256];
        #pragma unroll
        for (int off = 32; off > 0; off >>= 1) e += __shfl_down(e, off, 64);
        const int lane = t & 63;
        const int wid  = t >> 6;
        if (lane == 0) smem[wid] = e;
        __syncthreads();
        if (t == 0) out[0] = 0.5f * ((smem[0] + smem[1]) + (smem[2] + smem[3]));
        return;
    }

    const int i = blockIdx.x * 256 + threadIdx.x;
    if (i >= NPART) return;
    if (i >= MPART) {                   // zero pad regions [M:N), [N+M:2N)
        out[1 + i]         = 0.0f;
        out[1 + NPART + i] = 0.0f;
        return;
    }

    const float px = pos[i];
    const float py = pos[NPART + i];
    const float w  = nsx[i];
    const float h  = nsy[i];

    float gpx, gpy;
    const bool large = (w >= 1.0f) || (h >= 1.0f);
    if (!large) {
        int ix = min(max((int)floorf(px), 0), NBXC - 1);
        int iy = min(max((int)floorf(py), 0), NBYC - 1);
        const float wx = fminf(fmaxf(px - (float)ix, 0.0f), 1.0f);
        const float wy = fminf(fmaxf(py - (float)iy, 0.0f), 1.0f);
        const int ix1 = min(ix + 1, NBXC - 1);
        const int iy1 = min(iy + 1, NBYC - 1);
        const float2 f00 = __half22float2(v[tidx(ix,  iy )]);
        const float2 f10 = __half22float2(v[tidx(ix1, iy )]);
        const float2 f01 = __half22float2(v[tidx(ix,  iy1)]);
        const float2 f11 = __half22float2(v[tidx(ix1, iy1)]);
        const float w00 = (1.0f - wx) * (1.0f - wy);
        const float w10 = wx * (1.0f - wy);
        const float w01 = (1.0f - wx) * wy;
        const float w11 = wx * wy;
        gpx = w00 * f00.x + w10 * f10.x + w01 * f01.x + w11 * f11.x;
        gpy = w00 * f00.y + w10 * f10.y + w01 * f01.y + w11 * f11.y;
    } else {
        const float lx = px - 0.5f * w, rx = px + 0.5f * w;
        const float ly = py - 0.5f * h, ry = py + 0.5f * h;
        const int bminx = min(max((int)floorf(lx), 0), NBXC - 1);
        const int bmaxx = min(max((int)floorf(rx), 0), NBXC - 1);
        const int bminy = min(max((int)floorf(ly), 0), NBYC - 1);
        const int bmaxy = min(max((int)floorf(ry), 0), NBYC - 1);
        // 8-aligned y-window start: span<=7 + align<=7 -> always <=2 y-tiles
        const int by0 = min(bminy & ~7, NBYC - 16);
        const int ty0 = by0 >> 3;
        const int bx0 = bminx & ~1;                 // 2-aligned x start
        const bool y2 = (bmaxy - by0) >= 8;         // 2nd y-tile touched?

        float oy[16];
        #pragma unroll
        for (int k = 0; k < 16; ++k) {
            const int b = by0 + k;
            const float bl = (float)b;
            float ov = fminf(ry, bl + 1.0f) - fmaxf(ly, bl);
            oy[k] = (b <= bmaxy && ov > 0.0f) ? ov : 0.0f;
        }
        float ox[8];
        #pragma unroll
        for (int k = 0; k < 8; ++k) {
            const int b = bx0 + k;
            const float bl = (float)b;
            float ov = fminf(rx, bl + 1.0f) - fmaxf(lx, bl);
            ov = (b <= bmaxx && ov > 0.0f) ? ov : 0.0f;
            // bins below bminx get ov<=0 naturally (lx >= bminx when lx>=0)
            ox[k] = ov;
        }

        const float4 z = make_float4(0.0f, 0.0f, 0.0f, 0.0f);
        float afx = 0.0f, afy = 0.0f;
        #pragma unroll
        for (int p = 0; p < 4; ++p) {
            const float ov0 = ox[2 * p], ov1 = ox[2 * p + 1];
            if (ov0 > 0.0f || ov1 > 0.0f) {     // exec-masked tile-pair
                const float4* tp = reinterpret_cast<const float4*>(
                    v + (((((bx0 >> 1) + p) * 128 + ty0) << 4)));
                // sector 0 (y-tile ty0): row0 [0..7], row1 [0..7]
                float4 A0 = tp[0], A1 = tp[1], B0 = tp[2], B1 = tp[3];
                float4 A2 = z, A3 = z, B2 = z, B3 = z;
                if (y2) { A2 = tp[4]; A3 = tp[5]; B2 = tp[6]; B3 = tp[7]; }
                float sxa = 0.0f, sya = 0.0f, sxb = 0.0f, syb = 0.0f;
                const float* a0 = &A0.x; const float* a1 = &A1.x;
                const float* a2 = &A2.x; const float* a3 = &A3.x;
                const float* b0 = &B0.x; const float* b1 = &B1.x;
                const float* b2 = &B2.x; const float* b3 = &B3.x;
                #pragma unroll
                for (int e = 0; e < 4; ++e) {
                    float2 f;
                    f = __half22float2(__builtin_bit_cast(__half2, a0[e]));
                    sxa += f.x * oy[e];      sya += f.y * oy[e];
                    f = __half22float2(__builtin_bit_cast(__half2, a1[e]));
                    sxa += f.x * oy[4 + e];  sya += f.y * oy[4 + e];
                    f = __half22float2(__builtin_bit_cast(__half2, a2[e]));
                    sxa += f.x * oy[8 + e];  sya += f.y * oy[8 + e];
                    f = __half22float2(__builtin_bit_cast(__half2, a3[e]));
                    sxa += f.x * oy[12 + e]; sya += f.y * oy[12 + e];
                    f = __half22float2(__builtin_bit_cast(__half2, b0[e]));
                    sxb += f.x * oy[e];      syb += f.y * oy[e];
                    f = __half22float2(__builtin_bit_cast(__half2, b1[e]));
                    sxb += f.x * oy[4 + e];  syb += f.y * oy[4 + e];
                    f = __half22float2(__builtin_bit_cast(__half2, b2[e]));
                    sxb += f.x * oy[8 + e];  syb += f.y * oy[8 + e];
                    f = __half22float2(__builtin_bit_cast(__half2, b3[e]));
                    sxb += f.x * oy[12 + e]; syb += f.y * oy[12 + e];
                }
                afx += sxa * ov0 + sxb * ov1;
                afy += sya * ov0 + syb * ov1;
            }
        }
        const float inv = 1.0f / fmaxf(w * h, 1e-30f);
        gpx = afx * inv;
        gpy = afy * inv;
    }
    out[1 + i]         = gpx;
    out[1 + NPART + i] = gpy;
}

extern "C" void kernel_launch(void* const* d_in, const int* in_sizes, int n_in,
                              void* d_out, int out_size, void* d_ws, size_t ws_size,
                              hipStream_t stream) {
    const float* pos = (const float*)d_in[0];
    const float* pot = (const float*)d_in[1];
    const float* rho = (const float*)d_in[2];
    const float* nsx = (const float*)d_in[3];
    const float* nsy = (const float*)d_in[4];
    float* out = (float*)d_out;

    __half2* v      = (__half2*)d_ws;                                     // 4 MB (2x8 tiled)
    float* partials = (float*)((char*)d_ws + (size_t)NBXC * NBYC * sizeof(__half2));

    field_kernel<<<NPARTIAL, 256, 0, stream>>>(pot, rho, v, partials);
    particle_kernel<<<NBLK_PART + 1, 256, 0, stream>>>(pos, nsx, nsy, v, partials, out);
}